// Round 1
// baseline (3743.742 us; speedup 1.0000x reference)
//
#include <hip/hip_runtime.h>

#define E_CNT 80000
#define N_NODES 10000

__device__ __forceinline__ float sigmoidf_(float x) { return 1.f / (1.f + __expf(-x)); }

__device__ __forceinline__ unsigned fkey(float f) {
  unsigned u = __float_as_uint(f);
  return (u & 0x80000000u) ? ~u : (u | 0x80000000u);
}
__device__ __forceinline__ float unfkey(unsigned k) {
  unsigned u = (k & 0x80000000u) ? (k & 0x7FFFFFFFu) : ~k;
  return __uint_as_float(u);
}

// ---------------------------------------------------------------------------
// Phase 1: per-edge  x_edge -> rad MLP -> r[0:384];  wigner rows {0,2,6} x cat(x_src,x_tgt)
//          -> x0*r -> @c1_wm0[:, :576] -> (a: LN+smooth_leaky+alpha_dot -> alpha_pre),
//          (attn_out -> ws_attn)
// 16 edges per block, 256 threads.
// ---------------------------------------------------------------------------

__device__ __forceinline__ void k1_gemm3(const float* x0t, const float* __restrict__ w0,
                                         int col, float acc[16]) {
  const float4* x4 = (const float4*)x0t;
#pragma unroll
  for (int i = 0; i < 16; ++i) acc[i] = 0.f;
#pragma unroll 2
  for (int k = 0; k < 384; ++k) {
    float w = w0[(size_t)k * 768 + col];
    float4 a0 = x4[k * 5 + 0];
    float4 a1 = x4[k * 5 + 1];
    float4 a2 = x4[k * 5 + 2];
    float4 a3 = x4[k * 5 + 3];
    acc[0]  += a0.x * w; acc[1]  += a0.y * w; acc[2]  += a0.z * w; acc[3]  += a0.w * w;
    acc[4]  += a1.x * w; acc[5]  += a1.y * w; acc[6]  += a1.z * w; acc[7]  += a1.w * w;
    acc[8]  += a2.x * w; acc[9]  += a2.y * w; acc[10] += a2.z * w; acc[11] += a2.w * w;
    acc[12] += a3.x * w; acc[13] += a3.y * w; acc[14] += a3.z * w; acc[15] += a3.w * w;
  }
}

__global__ __launch_bounds__(256, 2) void k_phase1(
    const float* __restrict__ x, const int* __restrict__ an,
    const float* __restrict__ edist, const int* __restrict__ eidx,
    const float* __restrict__ wigner,
    const float* __restrict__ semb, const float* __restrict__ temb,
    const float* __restrict__ rw1, const float* __restrict__ rb1,
    const float* __restrict__ rlnw, const float* __restrict__ rlnb,
    const float* __restrict__ rw2, const float* __restrict__ rb2,
    const float* __restrict__ w0, const float* __restrict__ b0,
    const float* __restrict__ lnaw, const float* __restrict__ lnab,
    const float* __restrict__ adot,
    float* __restrict__ ws_attn, float* __restrict__ ws_apre)
{
  __shared__ __align__(16) float poolA[7680];   // xe[16][320] then x0t[384][20]
  __shared__ float sb[2048];                    // [16][128]
  __shared__ float rbuf[16 * 385];
  __shared__ float wgs[16 * 27];
  __shared__ int sidx[16], tidx[16], ansh[16], anth[16];

  const int tid = threadIdx.x;
  const int e0 = blockIdx.x * 16;

  if (tid < 16) {
    int s = eidx[e0 + tid], t = eidx[E_CNT + e0 + tid];
    sidx[tid] = s; tidx[tid] = t; ansh[tid] = an[s]; anth[tid] = an[t];
  }
  for (int i = tid; i < 16 * 27; i += 256) {
    int e = i / 27, r = i % 27, kk = r / 9, j = r % 9;
    int row = (kk == 0) ? 0 : (kk == 1 ? 2 : 6);
    wgs[i] = wigner[(size_t)(e0 + e) * 81 + row * 9 + j];
  }
  __syncthreads();

  // stage 1: gather x_edge
  float* xe = poolA;
  for (int i = tid; i < 16 * 320; i += 256) {
    int e = i / 320, c = i % 320;
    float v;
    if (c < 64)       v = edist[(size_t)(e0 + e) * 64 + c];
    else if (c < 192) v = semb[ansh[e] * 128 + (c - 64)];
    else              v = temb[anth[e] * 128 + (c - 192)];
    xe[e * 320 + c] = v;
  }
  __syncthreads();

  // stage 2: [16,320] @ rad_w1[320,128] + b1
  {
    int col = tid & 127, half = tid >> 7;
    float acc[8];
#pragma unroll
    for (int i = 0; i < 8; ++i) acc[i] = 0.f;
#pragma unroll 4
    for (int k = 0; k < 320; ++k) {
      float w = rw1[k * 128 + col];
#pragma unroll
      for (int i = 0; i < 8; ++i) acc[i] += xe[(half * 8 + i) * 320 + k] * w;
    }
    float bb = rb1[col];
#pragma unroll
    for (int i = 0; i < 8; ++i) sb[(half * 8 + i) * 128 + col] = acc[i] + bb;
  }
  __syncthreads();

  // stage 2b: LayerNorm(128) + scaled_silu
  {
    int wid = tid >> 6, lane = tid & 63;
    for (int e = wid; e < 16; e += 4) {
      float v0 = sb[e * 128 + lane], v1 = sb[e * 128 + lane + 64];
      float s1 = v0 + v1, s2 = v0 * v0 + v1 * v1;
#pragma unroll
      for (int m = 32; m >= 1; m >>= 1) {
        s1 += __shfl_xor(s1, m);
        s2 += __shfl_xor(s2, m);
      }
      float mu = s1 * (1.f / 128.f);
      float var = s2 * (1.f / 128.f) - mu * mu;
      float rstd = rsqrtf(var + 1e-5f);
      float y0 = (v0 - mu) * rstd * rlnw[lane] + rlnb[lane];
      float y1 = (v1 - mu) * rstd * rlnw[lane + 64] + rlnb[lane + 64];
      sb[e * 128 + lane]      = y0 * sigmoidf_(y0) * (1.f / 0.6f);
      sb[e * 128 + lane + 64] = y1 * sigmoidf_(y1) * (1.f / 0.6f);
    }
  }
  __syncthreads();

  // stage 3: [16,128] @ rad_w2[:, :384] + b2
  {
    int col128 = tid & 127, half = tid >> 7;
    for (int cc = 0; cc < 3; ++cc) {
      int col = cc * 128 + col128;
      float acc[8];
#pragma unroll
      for (int i = 0; i < 8; ++i) acc[i] = 0.f;
#pragma unroll 4
      for (int k = 0; k < 128; ++k) {
        float w = rw2[k * 768 + col];
#pragma unroll
        for (int i = 0; i < 8; ++i) acc[i] += sb[(half * 8 + i) * 128 + k] * w;
      }
      float bb = rb2[col];
#pragma unroll
      for (int i = 0; i < 8; ++i) rbuf[(half * 8 + i) * 385 + col] = acc[i] + bb;
    }
  }
  __syncthreads();

  // stage 4: wigner rows {0,2,6} x cat(x_src,x_tgt), scale by r -> x0t (transposed)
  float* x0t = poolA;  // xe is dead now
  {
    int e = tid & 15, cg = tid >> 4;
    int c0 = cg * 8;
    const float* xb = (c0 < 64) ? (x + (size_t)sidx[e] * 576 + c0)
                                : (x + (size_t)tidx[e] * 576 + (c0 - 64));
    float xc[9][8];
#pragma unroll
    for (int j = 0; j < 9; ++j) {
      float4 u0 = *(const float4*)(xb + j * 64);
      float4 u1 = *(const float4*)(xb + j * 64 + 4);
      xc[j][0] = u0.x; xc[j][1] = u0.y; xc[j][2] = u0.z; xc[j][3] = u0.w;
      xc[j][4] = u1.x; xc[j][5] = u1.y; xc[j][6] = u1.z; xc[j][7] = u1.w;
    }
#pragma unroll
    for (int kk = 0; kk < 3; ++kk) {
      float wv[9];
#pragma unroll
      for (int j = 0; j < 9; ++j) wv[j] = wgs[e * 27 + kk * 9 + j];
#pragma unroll
      for (int cu = 0; cu < 8; ++cu) {
        float m = 0.f;
#pragma unroll
        for (int j = 0; j < 9; ++j) m += wv[j] * xc[j][cu];
        int colc = kk * 128 + c0 + cu;
        x0t[colc * 20 + e] = m * rbuf[e * 385 + colc];
      }
    }
  }
  __syncthreads();

  // stage 5: [16,384] @ c1_wm0[:, :576] + b ; split into a-part / attn-part
  {
    // pass 0: cols 0..255 -> heads (LN32 + smooth_leaky + alpha_dot)
    float acc[16];
    k1_gemm3(x0t, w0, tid, acc);
    float bb = b0[tid];
    int h = tid >> 5, kk = tid & 31;
    float lw = lnaw[kk], lb = lnab[kk], ad = adot[h * 32 + kk];
    for (int e = 0; e < 16; ++e) {
      float v = acc[e] + bb;
      float s1 = v, s2 = v * v;
#pragma unroll
      for (int m = 16; m >= 1; m >>= 1) {
        s1 += __shfl_xor(s1, m);
        s2 += __shfl_xor(s2, m);
      }
      float mu = s1 * (1.f / 32.f);
      float var = s2 * (1.f / 32.f) - mu * mu;
      float rstd = rsqrtf(var + 1e-5f);
      float xn = (v - mu) * rstd * lw + lb;
      float sl = 0.6f * xn + 0.4f * xn * (2.f * sigmoidf_(xn) - 1.f);
      float p = sl * ad;
#pragma unroll
      for (int m = 16; m >= 1; m >>= 1) p += __shfl_xor(p, m);
      if (kk == 0) ws_apre[(size_t)(e0 + e) * 8 + h] = p;
    }
    // pass 1: cols 256..511 -> attn_out[0..255]
    k1_gemm3(x0t, w0, 256 + tid, acc);
    bb = b0[256 + tid];
#pragma unroll
    for (int e = 0; e < 16; ++e)
      ws_attn[(size_t)(e0 + e) * 320 + tid] = acc[e] + bb;
    // pass 2: cols 512..575 -> attn_out[256..319]
    if (tid < 64) {
      k1_gemm3(x0t, w0, 512 + tid, acc);
      bb = b0[512 + tid];
#pragma unroll
      for (int e = 0; e < 16; ++e)
        ws_attn[(size_t)(e0 + e) * 320 + 256 + tid] = acc[e] + bb;
    }
  }
}

// ---------------------------------------------------------------------------
// segment max / exp-sum for softmax over tgt
// ---------------------------------------------------------------------------
__global__ __launch_bounds__(256) void k_segmax(const float* __restrict__ apre,
                                                const int* __restrict__ eidx,
                                                unsigned* __restrict__ segk) {
  int idx = blockIdx.x * 256 + threadIdx.x;
  if (idx >= E_CNT * 8) return;
  int e = idx >> 3, h = idx & 7;
  int t = eidx[E_CNT + e];
  atomicMax(&segk[t * 8 + h], fkey(apre[idx]));
}

__global__ __launch_bounds__(256) void k_expsum(const float* __restrict__ apre,
                                                const int* __restrict__ eidx,
                                                const unsigned* __restrict__ segk,
                                                float* __restrict__ ex_out,
                                                float* __restrict__ denom) {
  int idx = blockIdx.x * 256 + threadIdx.x;
  if (idx >= E_CNT * 8) return;
  int e = idx >> 3, h = idx & 7;
  int t = eidx[E_CNT + e];
  float m = unfkey(segk[t * 8 + h]);
  float ex = __expf(apre[idx] - m);
  ex_out[idx] = ex;
  atomicAdd(&denom[t * 8 + h], ex);
}

// ---------------------------------------------------------------------------
// Phase 2: gates, message assembly, so2_conv2, alpha scale, wigner_inv,
// atomic scatter into node accumulator. 16 edges / block, 256 threads.
// ---------------------------------------------------------------------------
__global__ __launch_bounds__(256, 2) void k_phase2(
    const float* __restrict__ x, const int* __restrict__ eidx,
    const float* __restrict__ t_ij, const float* __restrict__ rl_ij,
    const float* __restrict__ winv,
    const float* __restrict__ gwh, const float* __restrict__ gwx, const float* __restrict__ gwt,
    const float* __restrict__ w0, const float* __restrict__ b0,
    const float* __restrict__ w1, const float* __restrict__ w2,
    const float* __restrict__ ws_attn, const float* __restrict__ ws_ex,
    const float* __restrict__ denom,
    float* __restrict__ node)
{
  __shared__ float ob[16 * 320];
  __shared__ float msg[16 * 576];
  __shared__ float wib[16 * 81];
  __shared__ float alp[16 * 8];
  __shared__ float rlb[16 * 8];
  __shared__ float malp[16];
  __shared__ int tnode[16];

  const int tid = threadIdx.x;
  const int e0 = blockIdx.x * 16;

  if (tid < 16) tnode[tid] = eidx[E_CNT + e0 + tid];
  __syncthreads();

  if (tid < 128) {
    int e = tid >> 3, h = tid & 7;
    float ex = ws_ex[(size_t)(e0 + e) * 8 + h];
    alp[tid] = ex / (denom[tnode[e] * 8 + h] + 1e-16f);
  } else {
    int i = tid - 128;
    int e = i >> 3;
    rlb[i] = rl_ij[(size_t)(e0 + e) * 8 + (i & 7)];
  }
  for (int i = tid; i < 16 * 81; i += 256) {
    int e = i / 81, r = i % 81;
    wib[i] = winv[(size_t)(e0 + e) * 81 + r];
  }
  // stage x[tgt] rows 0..8 into msg (as X_j source)
  for (int i = tid; i < 16 * 576; i += 256) {
    int e = i / 576, c = i % 576;
    msg[i] = x[(size_t)tnode[e] * 576 + c];
  }
  __syncthreads();
  if (tid < 16) {
    float s = 0.f;
#pragma unroll
    for (int h = 0; h < 8; ++h) s += alp[tid * 8 + h];
    malp[tid] = s * 0.125f;
  }
  __syncthreads();
  for (int i = tid; i < 16 * 320; i += 256) {
    int e = i / 320;
    ob[i] = malp[e] * ws_attn[(size_t)e0 * 320 + i];
  }
  __syncthreads();

  // gates: h = silu(h_j @ gwh), tp = silu(t_ij @ gwt), Xp = X_j @ gwx; build msg rows
  {
    int d = tid & 63, wid = tid >> 6;
    float acch[4] = {0.f, 0.f, 0.f, 0.f}, acct[4] = {0.f, 0.f, 0.f, 0.f};
#pragma unroll 4
    for (int k = 0; k < 64; ++k) {
      float w = gwh[k * 64 + d];
#pragma unroll
      for (int i = 0; i < 4; ++i) acch[i] += msg[(wid * 4 + i) * 576 + k] * w;
    }
#pragma unroll 4
    for (int k = 0; k < 128; ++k) {
      float w = gwt[k * 64 + d];
#pragma unroll
      for (int i = 0; i < 4; ++i) acct[i] += t_ij[(size_t)(e0 + wid * 4 + i) * 128 + k] * w;
    }
    float xp[4][8];
#pragma unroll
    for (int i = 0; i < 4; ++i)
#pragma unroll
      for (int k8 = 0; k8 < 8; ++k8) xp[i][k8] = 0.f;
#pragma unroll 2
    for (int c = 0; c < 64; ++c) {
      float w = gwx[c * 64 + d];
#pragma unroll
      for (int i = 0; i < 4; ++i) {
#pragma unroll
        for (int k8 = 0; k8 < 8; ++k8)
          xp[i][k8] += msg[(wid * 4 + i) * 576 + (k8 + 1) * 64 + c] * w;
      }
    }
    __syncthreads();   // all reads of staged x[tgt] complete
#pragma unroll
    for (int i = 0; i < 4; ++i) {
      int e = wid * 4 + i;
      float hv = acch[i]; hv = hv * sigmoidf_(hv);
      float tv = acct[i]; tv = tv * sigmoidf_(tv);
      float os  = ob[e * 320 + d];
      float od0 = ob[e * 320 + 64 + d],  od1 = ob[e * 320 + 128 + d];
      float ot0 = ob[e * 320 + 192 + d], ot1 = ob[e * 320 + 256 + d];
      msg[e * 576 + d] = os * hv;
#pragma unroll
      for (int j = 0; j < 3; ++j)
        msg[e * 576 + (1 + j) * 64 + d] = od0 * xp[i][j] + ot0 * tv * rlb[e * 8 + j];
#pragma unroll
      for (int j = 0; j < 5; ++j)
        msg[e * 576 + (4 + j) * 64 + d] = od1 * xp[i][3 + j] + ot1 * tv * rlb[e * 8 + 3 + j];
    }
  }
  __syncthreads();

  // so2_conv2 (per output channel c), alpha scale, wigner_inv, atomic scatter
  {
    int c = tid & 127, eh = tid >> 7;
    const int ebase = eh * 8;
    float m2[9][8];
    {  // wm0: x0 = msg rows {0,2,6}
      float a0[3][8];
#pragma unroll
      for (int q = 0; q < 3; ++q)
#pragma unroll
        for (int ee = 0; ee < 8; ++ee) a0[q][ee] = 0.f;
#pragma unroll 2
      for (int k = 0; k < 192; ++k) {
        int row = (k < 64) ? 0 : ((k < 128) ? 2 : 6);
        int src = row * 64 + (k & 63);
        float wA = w0[k * 384 + c];
        float wB = w0[k * 384 + 128 + c];
        float wC = w0[k * 384 + 256 + c];
#pragma unroll
        for (int ee = 0; ee < 8; ++ee) {
          float a = msg[(ebase + ee) * 576 + src];
          a0[0][ee] += a * wA; a0[1][ee] += a * wB; a0[2][ee] += a * wC;
        }
      }
      float bA = b0[c], bB = b0[128 + c], bC = b0[256 + c];
#pragma unroll
      for (int ee = 0; ee < 8; ++ee) {
        m2[0][ee] = a0[0][ee] + bA;
        m2[2][ee] = a0[1][ee] + bB;
        m2[6][ee] = a0[2][ee] + bC;
      }
    }
    {  // wm1: x1 rows [3|7] and [1|5]
      float y0[4][8], y1[4][8];
#pragma unroll
      for (int q = 0; q < 4; ++q)
#pragma unroll
        for (int ee = 0; ee < 8; ++ee) { y0[q][ee] = 0.f; y1[q][ee] = 0.f; }
#pragma unroll 2
      for (int k = 0; k < 128; ++k) {
        int s0 = (k < 64) ? (3 * 64 + k) : (7 * 64 + k - 64);
        int s1 = (k < 64) ? (1 * 64 + k) : (5 * 64 + k - 64);
        float wA = w1[k * 512 + c],       wB = w1[k * 512 + 128 + c];
        float wC = w1[k * 512 + 256 + c], wD = w1[k * 512 + 384 + c];
#pragma unroll
        for (int ee = 0; ee < 8; ++ee) {
          float aa = msg[(ebase + ee) * 576 + s0];
          float ab = msg[(ebase + ee) * 576 + s1];
          y0[0][ee] += aa * wA; y0[1][ee] += aa * wB; y0[2][ee] += aa * wC; y0[3][ee] += aa * wD;
          y1[0][ee] += ab * wA; y1[1][ee] += ab * wB; y1[2][ee] += ab * wC; y1[3][ee] += ab * wD;
        }
      }
#pragma unroll
      for (int ee = 0; ee < 8; ++ee) {
        m2[3][ee] = y0[0][ee] - y1[2][ee];
        m2[7][ee] = y0[1][ee] - y1[3][ee];
        m2[1][ee] = y1[0][ee] + y0[2][ee];
        m2[5][ee] = y1[1][ee] + y0[3][ee];
      }
    }
    {  // wm2: x2 rows 8 and 4
      float z0[2][8], z1[2][8];
#pragma unroll
      for (int q = 0; q < 2; ++q)
#pragma unroll
        for (int ee = 0; ee < 8; ++ee) { z0[q][ee] = 0.f; z1[q][ee] = 0.f; }
#pragma unroll 2
      for (int k = 0; k < 64; ++k) {
        float wA = w2[k * 256 + c], wB = w2[k * 256 + 128 + c];
#pragma unroll
        for (int ee = 0; ee < 8; ++ee) {
          float aa = msg[(ebase + ee) * 576 + 8 * 64 + k];
          float ab = msg[(ebase + ee) * 576 + 4 * 64 + k];
          z0[0][ee] += aa * wA; z0[1][ee] += aa * wB;
          z1[0][ee] += ab * wA; z1[1][ee] += ab * wB;
        }
      }
#pragma unroll
      for (int ee = 0; ee < 8; ++ee) {
        m2[8][ee] = z0[0][ee] - z1[1][ee];
        m2[4][ee] = z1[0][ee] + z0[1][ee];
      }
    }
    // alpha scale + wigner_inv + atomicAdd into node
    int h = c >> 4;
#pragma unroll
    for (int ee = 0; ee < 8; ++ee) {
      int e = ebase + ee;
      float av = alp[e * 8 + h];
      float mm[9];
#pragma unroll
      for (int j = 0; j < 9; ++j) mm[j] = m2[j][ee] * av;
      float* np = node + (size_t)tnode[e] * 1152 + c;
#pragma unroll
      for (int i = 0; i < 9; ++i) {
        float s = 0.f;
#pragma unroll
        for (int j = 0; j < 9; ++j) s += wib[e * 81 + i * 9 + j] * mm[j];
        atomicAdd(np + i * 128, s);
      }
    }
  }
}

// ---------------------------------------------------------------------------
// proj_w transpose + per-node projection
// ---------------------------------------------------------------------------
__global__ __launch_bounds__(256) void k_wt(const float* __restrict__ pw, float* __restrict__ wT) {
  int idx = blockIdx.x * 256 + threadIdx.x;
  if (idx >= 3 * 128 * 64) return;
  int l = idx / 8192, r = idx % 8192, i = r / 64, o = r % 64;
  wT[idx] = pw[(l * 64 + o) * 128 + i];
}

__global__ __launch_bounds__(256) void k_proj(const float* __restrict__ node,
                                              const float* __restrict__ wT,
                                              const float* __restrict__ pb,
                                              float* __restrict__ out) {
  __shared__ float A[32 * 132];
  int k = blockIdx.y;
  int n0 = blockIdx.x * 32;
  const int lidx = (k == 0) ? 0 : (k <= 3 ? 1 : 2);
  int tid = threadIdx.x;
  for (int i = tid; i < 32 * 128; i += 256) {
    int nn = i >> 7, ii = i & 127;
    int n = n0 + nn;
    A[nn * 132 + ii] = (n < N_NODES) ? node[((size_t)n * 9 + k) * 128 + ii] : 0.f;
  }
  __syncthreads();
  int o = tid & 63, wid = tid >> 6;
  float acc[8] = {0.f, 0.f, 0.f, 0.f, 0.f, 0.f, 0.f, 0.f};
#pragma unroll 4
  for (int i = 0; i < 128; ++i) {
    float w = wT[lidx * 8192 + i * 64 + o];
#pragma unroll
    for (int r = 0; r < 8; ++r) acc[r] += A[(wid * 8 + r) * 132 + i] * w;
  }
  float bias = (k == 0) ? pb[o] : 0.f;
#pragma unroll
  for (int r = 0; r < 8; ++r) {
    int n = n0 + wid * 8 + r;
    if (n < N_NODES) out[((size_t)n * 9 + k) * 64 + o] = acc[r] + bias;
  }
}

// ---------------------------------------------------------------------------
extern "C" void kernel_launch(void* const* d_in, const int* in_sizes, int n_in,
                              void* d_out, int out_size, void* d_ws, size_t ws_size,
                              hipStream_t stream) {
  const float* x      = (const float*)d_in[0];
  const int*   an     = (const int*)d_in[1];
  const float* edist  = (const float*)d_in[2];
  const int*   eidx   = (const int*)d_in[3];
  const float* t_ij   = (const float*)d_in[4];
  const float* rl_ij  = (const float*)d_in[5];
  const float* wig    = (const float*)d_in[6];
  const float* winv   = (const float*)d_in[7];
  const float* semb   = (const float*)d_in[8];
  const float* temb   = (const float*)d_in[9];
  const float* rw1    = (const float*)d_in[10];
  const float* rb1    = (const float*)d_in[11];
  const float* rlnw   = (const float*)d_in[12];
  const float* rlnb   = (const float*)d_in[13];
  const float* rw2    = (const float*)d_in[14];
  const float* rb2    = (const float*)d_in[15];
  const float* c1w0   = (const float*)d_in[16];
  const float* c1b0   = (const float*)d_in[17];
  // d_in[18], d_in[19]: c1_wm1 / c1_wm2 — dead code in the reference (output discarded)
  const float* lnaw   = (const float*)d_in[20];
  const float* lnab   = (const float*)d_in[21];
  const float* adot   = (const float*)d_in[22];
  const float* gwh    = (const float*)d_in[23];
  const float* gwx    = (const float*)d_in[24];
  const float* gwt    = (const float*)d_in[25];
  const float* c2w0   = (const float*)d_in[26];
  const float* c2b0   = (const float*)d_in[27];
  const float* c2w1   = (const float*)d_in[28];
  const float* c2w2   = (const float*)d_in[29];
  const float* pw     = (const float*)d_in[30];
  const float* pb     = (const float*)d_in[31];
  float* out = (float*)d_out;

  char* p = (char*)d_ws;
  float* ws_attn  = (float*)p; p += (size_t)E_CNT * 320 * 4;
  float* ws_apre  = (float*)p; p += (size_t)E_CNT * 8 * 4;
  float* ws_ex    = (float*)p; p += (size_t)E_CNT * 8 * 4;
  unsigned* segk  = (unsigned*)p; p += (size_t)N_NODES * 8 * 4;
  float* denom    = (float*)p; p += (size_t)N_NODES * 8 * 4;
  float* node     = (float*)p; p += (size_t)N_NODES * 1152 * 4;
  float* wT       = (float*)p; p += (size_t)3 * 128 * 64 * 4;

  hipMemsetAsync(segk, 0, N_NODES * 8 * 4, stream);
  hipMemsetAsync(denom, 0, N_NODES * 8 * 4, stream);
  hipMemsetAsync(node, 0, (size_t)N_NODES * 1152 * 4, stream);

  k_wt<<<96, 256, 0, stream>>>(pw, wT);
  k_phase1<<<E_CNT / 16, 256, 0, stream>>>(x, an, edist, eidx, wig, semb, temb,
                                           rw1, rb1, rlnw, rlnb, rw2, rb2,
                                           c1w0, c1b0, lnaw, lnab, adot,
                                           ws_attn, ws_apre);
  k_segmax<<<(E_CNT * 8) / 256, 256, 0, stream>>>(ws_apre, eidx, segk);
  k_expsum<<<(E_CNT * 8) / 256, 256, 0, stream>>>(ws_apre, eidx, segk, ws_ex, denom);
  k_phase2<<<E_CNT / 16, 256, 0, stream>>>(x, eidx, t_ij, rl_ij, winv,
                                           gwh, gwx, gwt, c2w0, c2b0, c2w1, c2w2,
                                           ws_attn, ws_ex, denom, node);
  k_proj<<<dim3((N_NODES + 31) / 32, 9), 256, 0, stream>>>(node, wT, pb, out);
}